// Round 7
// baseline (3002.888 us; speedup 1.0000x reference)
//
#include <hip/hip_runtime.h>

typedef _Float16 fp16_t;
typedef _Float16 v8h __attribute__((ext_vector_type(8)));
typedef float    v4f __attribute__((ext_vector_type(4)));

#define RELAX_LR 0.3f

// async global->LDS, 16B per lane. LDS dest = wave-uniform base + lane*16.
__device__ __forceinline__ void async_cp16(const void* g, void* l) {
    __builtin_amdgcn_global_load_lds(
        (const __attribute__((address_space(1))) void*)g,
        (__attribute__((address_space(3))) void*)l, 16, 0, 0);
}

// GEMM job: C_partial(z) = A1*B1t^T (concat K-space [0,K1)) ++ A2*B2t^T
// ([K1,K1+K2s)). Chunk z covers [z*CK,(z+1)*CK); K1 and CK are multiples of
// BK=32 so a BK-tile never straddles the section boundary.
struct GJob {
    const fp16_t *A1, *B1t, *A2, *B2t;
    fp16_t* part;
    int K1, K2s, CK, Ntot;
};

// ---------------------------------------------------------------------------
// r6: 256x256 tile, 8 waves (512 thr), BK=32, phase-split counted-vmcnt
// schedule (T3+T4), LDS slot-XOR swizzle (T2), setprio around MFMA (T5).
// Wave tile 128x64 (8x4 16x16x32 f16 frags) -> per CU per K=32: 96 ds_read
// vs 256 MFMA = MFMA-bound (the 64x64-wave r0 structure was LDS-read-bound:
// 128 reads vs 256 MFMA; r5 proved faster MFMA alone doesn't pay there).
// 3-buffer LDS ring (96KB, 1 block/CU): staging runs one full K-tile ahead;
// per-tile gate = per-wave `s_waitcnt vmcnt(4)` BEFORE the rendezvous
// barrier (all waves certify their own staged loads, barrier publishes) --
// never a full drain in steady state. Two phases per K-tile, each:
// {stage 1 half (2 cp16/wave), ds_read frags, s_barrier, lgkmcnt(0),
//  setprio(1), 16 MFMA, setprio(0), s_barrier}. The post-MFMA barrier makes
// ring reuse safe: each wave's lgkmcnt(0) retires its reads before it, so a
// stage issued after it can never overwrite in-flight reads.
// Bank swizzle (both-sides, r5-proven scheme): 64B rows = 4 16B slots;
// physical slot = logical ^ (row&3); applied as lane-only XOR on the GLOBAL
// source ((lane&3)^(lane>>2&3)) since global_load_lds writes linearly, and
// as XOR'd slot on ds_read ((quad)^(lrow&3)).
// z pinned per XCD (blk&7): per-XCD L2 set = A(1MB)+B(<=2MB) < 4MB.
// NO device fences anywhere (r4: per-block threadfence = L2 flush storm, 6x).
// ---------------------------------------------------------------------------
__global__ __launch_bounds__(512, 2) void gemm_splitk_kernel(GJob j0, GJob j1, int nb0)
{
    __shared__ __align__(16) fp16_t smem[3][2][256][32];  // [buf][A|B][row][k] 96KB

    const int tid  = threadIdx.x;
    const int lane = tid & 63;
    const int w    = tid >> 6;         // wave 0..7
    const int wr   = w >> 2;           // M-half (128 rows)
    const int wc   = w & 3;            // N-quarter (64 cols)
    const int quad = lane >> 4;
    const int lrow = lane & 15;

    int bblk = blockIdx.x;
    const GJob j = (bblk < nb0) ? j0 : j1;       // block-uniform
    if (bblk >= nb0) bblk -= nb0;

    // decode: blk&7 = XCD = z; idx enumerates (bm,bn).
    const int xcd = bblk & 7;
    const int idx = bblk >> 3;
    int bm, bn;
    if (j.Ntot == 2048) { bm = idx >> 3; bn = idx & 7; }   // 4x8 tiles, 256 blks
    else                { bm = idx >> 2; bn = idx & 3; }   // 4x4 tiles, 128 blks
    const int z  = xcd;
    const int k0 = z * j.CK;
    const int nt = j.CK >> 5;          // BK = 32 tiles

    // staging geometry: per cp16 a wave covers 16 rows x 64B; lane ->
    // (row=lane/4, slot=lane&3); source col-slot pre-swizzled by ^(row&3)
    // so LDS physical slot q of row r holds logical slot q^(r&3).
    const int srow = lane >> 2;
    const int swz  = ((lane & 3) ^ (srow & 3)) * 8;
    const int arow = bm * 256 + w * 16 + srow;
    const int brow = bn * 256 + w * 16 + srow;
    const fp16_t* a1 = j.A1  + (size_t)arow * j.K1 + swz;
    const fp16_t* b1 = j.B1t + (size_t)brow * j.K1 + swz;
    const fp16_t* a2 = j.A2  ? j.A2  + (size_t)arow * j.K2s + swz : nullptr;
    const fp16_t* b2 = j.B2t ? j.B2t + (size_t)brow * j.K2s + swz : nullptr;

    auto stageA = [&](int buf, int kc) {       // 2 cp16: rows [w*16) and [128+w*16)
        const fp16_t* s; size_t st;
        if (kc < j.K1) { s = a1 + kc;          st = (size_t)128 * j.K1;  }
        else           { s = a2 + (kc - j.K1); st = (size_t)128 * j.K2s; }
        async_cp16(s,      &smem[buf][0][w * 16][0]);
        async_cp16(s + st, &smem[buf][0][128 + w * 16][0]);
    };
    auto stageB = [&](int buf, int kc) {
        const fp16_t* s; size_t st;
        if (kc < j.K1) { s = b1 + kc;          st = (size_t)128 * j.K1;  }
        else           { s = b2 + (kc - j.K1); st = (size_t)128 * j.K2s; }
        async_cp16(s,      &smem[buf][1][w * 16][0]);
        async_cp16(s + st, &smem[buf][1][128 + w * 16][0]);
    };

    v4f acc[8][4] = {};

    // prologue: tiles 0 and 1 staged (4 cp16/wave each); gate tile 0.
    stageA(0, k0);          stageB(0, k0);
    stageA(1, k0 + 32);     stageB(1, k0 + 32);
    asm volatile("s_waitcnt vmcnt(4)" ::: "memory");   // tile0 landed (mine)
    __builtin_amdgcn_s_barrier();                      // publish: all waves'

    int cur = 0;
    for (int t = 0; t < nt; ++t) {
        const int nx2 = (cur + 2 >= 3) ? cur - 1 : cur + 2;   // (t+2)%3
        const bool pf = (t + 2 < nt);
        v8h Af[4], Bf[4];

        // ---- phase 0: stage A(t+2) | read A0-3,B0-3 | MFMA fm0-3 ----
        if (pf) stageA(nx2, k0 + (t + 2) * 32);
        #pragma unroll
        for (int fm = 0; fm < 4; ++fm)
            Af[fm] = *(const v8h*)&smem[cur][0][wr * 128 + fm * 16 + lrow]
                                        [(quad ^ (lrow & 3)) * 8];
        #pragma unroll
        for (int fn = 0; fn < 4; ++fn)
            Bf[fn] = *(const v8h*)&smem[cur][1][wc * 64 + fn * 16 + lrow]
                                        [(quad ^ (lrow & 3)) * 8];
        __builtin_amdgcn_s_barrier();
        asm volatile("s_waitcnt lgkmcnt(0)" ::: "memory");
        __builtin_amdgcn_sched_barrier(0);
        __builtin_amdgcn_s_setprio(1);
        #pragma unroll
        for (int fm = 0; fm < 4; ++fm)
            #pragma unroll
            for (int fn = 0; fn < 4; ++fn)
                acc[fm][fn] = __builtin_amdgcn_mfma_f32_16x16x32_f16(
                    Af[fm], Bf[fn], acc[fm][fn], 0, 0, 0);
        __builtin_amdgcn_s_setprio(0);
        __builtin_amdgcn_s_barrier();   // reads of buf cur (ph0) retired

        // ---- phase 1: stage B(t+2) | read A4-7 (Bf reused) | MFMA fm4-7 ----
        if (pf) stageB(nx2, k0 + (t + 2) * 32);
        #pragma unroll
        for (int fm = 0; fm < 4; ++fm)
            Af[fm] = *(const v8h*)&smem[cur][0][wr * 128 + (4 + fm) * 16 + lrow]
                                        [(quad ^ (lrow & 3)) * 8];
        __builtin_amdgcn_s_barrier();
        asm volatile("s_waitcnt lgkmcnt(0)" ::: "memory");
        __builtin_amdgcn_sched_barrier(0);
        __builtin_amdgcn_s_setprio(1);
        #pragma unroll
        for (int fm = 0; fm < 4; ++fm)
            #pragma unroll
            for (int fn = 0; fn < 4; ++fn)
                acc[4 + fm][fn] = __builtin_amdgcn_mfma_f32_16x16x32_f16(
                    Af[fm], Bf[fn], acc[4 + fm][fn], 0, 0, 0);
        __builtin_amdgcn_s_setprio(0);
        // per-tile gate for tile t+1, BEFORE the barrier that opens it:
        if (pf)                 asm volatile("s_waitcnt vmcnt(4)" ::: "memory");
        else if (t + 1 < nt)    asm volatile("s_waitcnt vmcnt(0)" ::: "memory");
        __builtin_amdgcn_s_barrier();
        cur = (cur + 1 == 3) ? 0 : cur + 1;
    }

    // write fp16 partials. 16x16x32 C/D: col = lane&15, row = quad*4 + reg.
    fp16_t* po = j.part + (size_t)z * 1024 * j.Ntot;
    const int rowb = bm * 256 + wr * 128 + quad * 4;
    const int colb = bn * 256 + wc * 64 + lrow;
    #pragma unroll
    for (int fn = 0; fn < 4; ++fn) {
        const int col = colb + fn * 16;
        #pragma unroll
        for (int fm = 0; fm < 8; ++fm) {
            const int row0 = rowb + fm * 16;
            #pragma unroll
            for (int r = 0; r < 4; ++r)
                po[(size_t)(row0 + r) * j.Ntot + col] = (fp16_t)acc[fm][fn][r];
        }
    }
}

// Reduce job: sum nz fp16 partial slices + (bias[col] OR per-element fp32
// extra), optional relax-update vs s_old, clip, fp16 state write; optional
// fp32 final output stripped to [1024,1000].
struct RJob {
    const fp16_t* part;
    const float* bias;
    const float* extra;
    const fp16_t* s_old;
    fp16_t* outb;
    float* finout;
    int nz, Ntot, do_update;
};

__global__ __launch_bounds__(256) void reduce_update_kernel(RJob j0, RJob j1, int nb0)
{
    int b = blockIdx.x;
    const RJob j = (b < nb0) ? j0 : j1;          // block-uniform
    if (b >= nb0) b -= nb0;
    const size_t e = ((size_t)b * 256 + threadIdx.x) * 8;  // grids sized exactly

    float v[8];
    {
        const v8h p0 = *(const v8h*)(j.part + e);
        #pragma unroll
        for (int k = 0; k < 8; ++k) v[k] = (float)p0[k];
    }
    for (int z = 1; z < j.nz; ++z) {
        const v8h p = *(const v8h*)(j.part + (size_t)z * 1024 * j.Ntot + e);
        #pragma unroll
        for (int k = 0; k < 8; ++k) v[k] += (float)p[k];
    }
    const int col = (int)e & (j.Ntot - 1);
    if (j.extra) {
        const float4 e0 = *(const float4*)(j.extra + e);
        const float4 e1 = *(const float4*)(j.extra + e + 4);
        v[0] += e0.x; v[1] += e0.y; v[2] += e0.z; v[3] += e0.w;
        v[4] += e1.x; v[5] += e1.y; v[6] += e1.z; v[7] += e1.w;
    } else {
        const float4 b0 = *(const float4*)(j.bias + col);
        const float4 b1 = *(const float4*)(j.bias + col + 4);
        v[0] += b0.x; v[1] += b0.y; v[2] += b0.z; v[3] += b0.w;
        v[4] += b1.x; v[5] += b1.y; v[6] += b1.z; v[7] += b1.w;
    }
    if (j.do_update) {
        const v8h so = *(const v8h*)(j.s_old + e);
        #pragma unroll
        for (int k = 0; k < 8; ++k) {
            const float s = (float)so[k];
            v[k] = s + RELAX_LR * (v[k] - s);
        }
    }
    #pragma unroll
    for (int k = 0; k < 8; ++k) v[k] = fminf(fmaxf(v[k], 0.f), 1.f);
    v8h h;
    #pragma unroll
    for (int k = 0; k < 8; ++k) h[k] = (fp16_t)v[k];
    *(v8h*)(j.outb + e) = h;

    if (j.finout && col < 1000) {
        const int row = (int)(e >> 10);          // Ntot == 1024 on this path
        float* o = j.finout + (size_t)row * 1000 + col;
        float4 o0 = {v[0], v[1], v[2], v[3]};
        float4 o1 = {v[4], v[5], v[6], v[7]};
        *(float4*)o       = o0;
        *(float4*)(o + 4) = o1;
    }
}

// c1f = sum of 8 fp16 partial slices + bias (fp32, no clip): the
// loop-invariant layer-1 constant b1 + rho(x)@W0, computed once.
__global__ __launch_bounds__(256) void makec1_kernel(
    const fp16_t* __restrict__ part, const float* __restrict__ bias,
    float* __restrict__ c1f, int total8)
{
    const int i = blockIdx.x * 256 + threadIdx.x;
    if (i >= total8) return;
    const size_t e = (size_t)i * 8;
    float v[8];
    {
        const v8h p0 = *(const v8h*)(part + e);
        #pragma unroll
        for (int k = 0; k < 8; ++k) v[k] = (float)p0[k];
    }
    #pragma unroll
    for (int z = 1; z < 8; ++z) {
        const v8h p = *(const v8h*)(part + (size_t)z * 1024 * 2048 + e);
        #pragma unroll
        for (int k = 0; k < 8; ++k) v[k] += (float)p[k];
    }
    const int col = (int)e & 2047;
    const float4 b0 = *(const float4*)(bias + col);
    const float4 b1 = *(const float4*)(bias + col + 4);
    v[0] += b0.x; v[1] += b0.y; v[2] += b0.z; v[3] += b0.w;
    v[4] += b1.x; v[5] += b1.y; v[6] += b1.z; v[7] += b1.w;
    float4 o0 = {v[0], v[1], v[2], v[3]};
    float4 o1 = {v[4], v[5], v[6], v[7]};
    *(float4*)(c1f + e)     = o0;
    *(float4*)(c1f + e + 4) = o1;
}

// fp32 W [R,C] -> fp16 Wb [Rp,Cp] (optional) + fp16 WbT [Cp,Rp], zero-padded.
__global__ void conv_w_kernel(const float* __restrict__ W, int R, int C,
                              fp16_t* Wb, fp16_t* __restrict__ WbT,
                              int Rp, int Cp)
{
    __shared__ float t[32][33];
    const int tx = threadIdx.x & 31;
    const int ty = threadIdx.x >> 5;   // 0..7
    const int r0 = blockIdx.y * 32;
    const int c0 = blockIdx.x * 32;
    #pragma unroll
    for (int i = 0; i < 4; ++i) {
        const int r = r0 + ty + i * 8;
        const int c = c0 + tx;
        float v = 0.f;
        if (r < R && c < C) v = W[(size_t)r * C + c];
        t[ty + i * 8][tx] = v;
    }
    __syncthreads();
    if (Wb) {
        #pragma unroll
        for (int i = 0; i < 4; ++i) {
            const int r = r0 + ty + i * 8;
            const int c = c0 + tx;
            if (r < Rp && c < Cp) Wb[(size_t)r * Cp + c] = (fp16_t)t[ty + i * 8][tx];
        }
    }
    #pragma unroll
    for (int i = 0; i < 4; ++i) {
        const int cc = c0 + ty + i * 8;
        const int rr = r0 + tx;
        if (cc < Cp && rr < Rp) WbT[(size_t)cc * Rp + rr] = (fp16_t)t[tx][ty + i * 8];
    }
}

__global__ void conv_x_kernel(const float* __restrict__ x,
                              fp16_t* __restrict__ xb, fp16_t* __restrict__ rxb, int n)
{
    const int i = blockIdx.x * blockDim.x + threadIdx.x;
    if (i < n) {
        const float v = x[i];
        xb[i]  = (fp16_t)v;
        rxb[i] = (fp16_t)fminf(fmaxf(v, 0.f), 1.f);
    }
}

__global__ void pad_b4_kernel(const float* __restrict__ b4, float* __restrict__ b4p)
{
    const int i = blockIdx.x * blockDim.x + threadIdx.x;
    if (i < 1024) b4p[i] = (i < 1000) ? b4[i] : 0.f;
}

extern "C" void kernel_launch(void* const* d_in, const int* in_sizes, int n_in,
                              void* d_out, int out_size, void* d_ws, size_t ws_size,
                              hipStream_t stream)
{
    const float* x  = (const float*)d_in[0];
    const float* W0 = (const float*)d_in[1];
    const float* W1 = (const float*)d_in[2];
    const float* W2 = (const float*)d_in[3];
    const float* W3 = (const float*)d_in[4];
    const float* b1 = (const float*)d_in[5];
    const float* b2 = (const float*)d_in[6];
    const float* b3 = (const float*)d_in[7];
    const float* b4 = (const float*)d_in[8];
    float* out = (float*)d_out;

    char* p = (char*)d_ws;
    auto alloc = [&](size_t bytes) {
        char* q = p;
        p += (bytes + 255) & ~(size_t)255;
        return q;
    };

    fp16_t* xb    = (fp16_t*)alloc((size_t)1024 * 2048 * 2);
    fp16_t* rxb   = (fp16_t*)alloc((size_t)1024 * 2048 * 2);
    fp16_t* Wb1   = (fp16_t*)alloc((size_t)2048 * 2048 * 2);
    fp16_t* Wb2   = (fp16_t*)alloc((size_t)2048 * 2048 * 2);
    fp16_t* Wb3   = (fp16_t*)alloc((size_t)2048 * 1024 * 2);   // padded cols
    fp16_t* WbT0  = (fp16_t*)alloc((size_t)2048 * 2048 * 2);
    fp16_t* WbT1  = (fp16_t*)alloc((size_t)2048 * 2048 * 2);
    fp16_t* WbT2  = (fp16_t*)alloc((size_t)2048 * 2048 * 2);
    fp16_t* WbT3  = (fp16_t*)alloc((size_t)1024 * 2048 * 2);   // padded rows
    fp16_t* s1b   = (fp16_t*)alloc((size_t)1024 * 2048 * 2);
    fp16_t* s2b   = (fp16_t*)alloc((size_t)1024 * 2048 * 2);
    fp16_t* s3b   = (fp16_t*)alloc((size_t)1024 * 2048 * 2);
    fp16_t* s4b   = (fp16_t*)alloc((size_t)1024 * 1024 * 2);
    float*  b4p   = (float*)alloc(1024 * 4);
    float*  c1f   = (float*)alloc((size_t)1024 * 2048 * 4);    // hoisted b1+rho(x)@W0
    fp16_t* partA = (fp16_t*)alloc((size_t)8 * 1024 * 1024 * 2); // 16 MB (Ntot=1024, z=8)
    fp16_t* partB = (fp16_t*)alloc((size_t)8 * 1024 * 2048 * 2); // 32 MB (Ntot=2048, z=8)
    (void)ws_size; (void)in_sizes; (void)n_in; (void)out_size;

    // --- setup conversions ---
    conv_x_kernel<<<(1024 * 2048 + 255) / 256, 256, 0, stream>>>(x, xb, rxb, 1024 * 2048);
    pad_b4_kernel<<<4, 256, 0, stream>>>(b4, b4p);
    conv_w_kernel<<<dim3(64, 64), 256, 0, stream>>>(W0, 2048, 2048, nullptr, WbT0, 2048, 2048);
    conv_w_kernel<<<dim3(64, 64), 256, 0, stream>>>(W1, 2048, 2048, Wb1, WbT1, 2048, 2048);
    conv_w_kernel<<<dim3(64, 64), 256, 0, stream>>>(W2, 2048, 2048, Wb2, WbT2, 2048, 2048);
    conv_w_kernel<<<dim3(32, 64), 256, 0, stream>>>(W3, 2048, 1000, Wb3, WbT3, 2048, 1024);

    const dim3 blk(512);               // GEMM: 8 waves
    const dim3 rblk(256);
    const int rg2048 = 1024 * 2048 / 8 / 256;   // 1024 blocks
    const int rg1024 = 1024 * 1024 / 8 / 256;   // 512 blocks

    // --- GEMM jobs (A1,B1t,A2,B2t,part,K1,K2s,CK,Ntot); z=8 always ---
    const GJob jC1 = { rxb, WbT0, nullptr, nullptr, partB, 2048, 0,    256, 2048 };
    const GJob jI1 = { xb,  WbT0, nullptr, nullptr, partB, 2048, 0,    256, 2048 };
    const GJob jI2 = { s1b, WbT1, nullptr, nullptr, partB, 2048, 0,    256, 2048 };
    const GJob jI3 = { s2b, WbT2, nullptr, nullptr, partB, 2048, 0,    256, 2048 };
    const GJob jI4 = { s3b, WbT3, nullptr, nullptr, partA, 2048, 0,    256, 1024 };
    const GJob jL1 = { s2b, Wb1,  nullptr, nullptr, partB, 2048, 0,    256, 2048 };
    const GJob jL2 = { s1b, WbT1, s3b, Wb2,         partB, 2048, 2048, 512, 2048 };
    const GJob jL3 = { s2b, WbT2, s4b, Wb3,         partB, 2048, 1024, 384, 2048 };
    const GJob jL4 = { s3b, WbT3, nullptr, nullptr, partA, 2048, 0,    256, 1024 };

    // --- reduce jobs (part,bias,extra,s_old,outb,finout,nz,Ntot,do_update) ---
    const RJob rI1 = { partB, b1,  nullptr, nullptr, s1b, nullptr, 8, 2048, 0 };
    const RJob rI2 = { partB, b2,  nullptr, nullptr, s2b, nullptr, 8, 2048, 0 };
    const RJob rI3 = { partB, b3,  nullptr, nullptr, s3b, nullptr, 8, 2048, 0 };
    const RJob rI4 = { partA, b4p, nullptr, nullptr, s4b, nullptr, 8, 1024, 0 };
    const RJob rL1 = { partB, nullptr, c1f, s1b, s1b, nullptr, 8, 2048, 1 };
    const RJob rL2 = { partB, b2,  nullptr, s2b, s2b, nullptr, 8, 2048, 1 };
    const RJob rL3 = { partB, b3,  nullptr, s3b, s3b, nullptr, 8, 2048, 1 };
    const RJob rL4 = { partA, b4p, nullptr, s4b, s4b, nullptr, 8, 1024, 1 };
    RJob rL4f = rL4; rL4f.finout = out;

    // --- hoisted layer-1 constant: c1f = b1 + rho(x)@W0 (once, reused 25x) ---
    gemm_splitk_kernel<<<256, blk, 0, stream>>>(jC1, jC1, 256);
    makec1_kernel<<<rg2048, rblk, 0, stream>>>(partB, b1, c1f, 1024 * 2048 / 8);

    // --- feedforward init: s_l = clip(s_{l-1} @ W_{l-1} + b_l) ---
    gemm_splitk_kernel<<<256, blk, 0, stream>>>(jI1, jI1, 256);
    reduce_update_kernel<<<rg2048, rblk, 0, stream>>>(rI1, rI1, rg2048);
    gemm_splitk_kernel<<<256, blk, 0, stream>>>(jI2, jI2, 256);
    reduce_update_kernel<<<rg2048, rblk, 0, stream>>>(rI2, rI2, rg2048);
    gemm_splitk_kernel<<<256, blk, 0, stream>>>(jI3, jI3, 256);
    reduce_update_kernel<<<rg2048, rblk, 0, stream>>>(rI3, rI3, rg2048);
    gemm_splitk_kernel<<<128, blk, 0, stream>>>(jI4, jI4, 128);
    reduce_update_kernel<<<rg1024, rblk, 0, stream>>>(rI4, rI4, rg1024);

    // --- 25 Gauss-Seidel sweeps. Layer order per sweep is L1,L2,L3,L4, but
    // L4(sweep it) and L1(sweep it+1) are mutually independent (L4 reads s3,
    // L1 reads s2 + c1f) -> merged into one GEMM + one reduce dispatch. ---
    gemm_splitk_kernel<<<256, blk, 0, stream>>>(jL1, jL1, 256);          // L1, sweep 0
    reduce_update_kernel<<<rg2048, rblk, 0, stream>>>(rL1, rL1, rg2048);
    for (int it = 0; it < 25; ++it) {
        gemm_splitk_kernel<<<256, blk, 0, stream>>>(jL2, jL2, 256);
        reduce_update_kernel<<<rg2048, rblk, 0, stream>>>(rL2, rL2, rg2048);
        gemm_splitk_kernel<<<256, blk, 0, stream>>>(jL3, jL3, 256);
        reduce_update_kernel<<<rg2048, rblk, 0, stream>>>(rL3, rL3, rg2048);
        if (it < 24) {
            gemm_splitk_kernel<<<384, blk, 0, stream>>>(jL4, jL1, 128);  // L4 + next L1
            reduce_update_kernel<<<rg1024 + rg2048, rblk, 0, stream>>>(rL4, rL1, rg1024);
        } else {
            gemm_splitk_kernel<<<128, blk, 0, stream>>>(jL4, jL4, 128);
            reduce_update_kernel<<<rg1024, rblk, 0, stream>>>(rL4f, rL4f, rg1024);
        }
    }
}

// Round 8
// 2669.246 us; speedup vs baseline: 1.1250x; 1.1250x over previous
//
#include <hip/hip_runtime.h>

typedef _Float16 fp16_t;
typedef _Float16 v8h __attribute__((ext_vector_type(8)));
typedef float    v4f __attribute__((ext_vector_type(4)));

#define RELAX_LR 0.3f

// async global->LDS, 16B per lane. LDS dest = wave-uniform base + lane*16.
__device__ __forceinline__ void async_cp16(const void* g, void* l) {
    __builtin_amdgcn_global_load_lds(
        (const __attribute__((address_space(1))) void*)g,
        (__attribute__((address_space(3))) void*)l, 16, 0, 0);
}

// GEMM job: C_partial(z) = A1*B1t^T (concat K-space [0,K1)) ++ A2*B2t^T
// ([K1,K1+K2s)). Chunk z covers [z*CK,(z+1)*CK); K1 and CK are multiples of
// BK=32 so a BK-tile never straddles the section boundary (pointer select
// per BK-iter is block-uniform scalar work).
struct GJob {
    const fp16_t *A1, *B1t, *A2, *B2t;
    fp16_t* part;
    int K1, K2s, CK, Ntot;
};

// ---------------------------------------------------------------------------
// r8 = r0 (session best, 2407us) with ONLY the K-loop sync changed:
// BK 64->32 + 3-buffer LDS ring (48KB, still 2 blocks/CU like r0) +
// counted-vmcnt gate. r0's __syncthreads drains vmcnt(0) every iter (the
// documented m97-class stall); here stage(t+2) is in flight while tile t
// computes, and the per-iter gate is `s_waitcnt vmcnt(4)` + ONE raw
// s_barrier -- a full drain only on the last tile.
// Ledger: prologue stages tiles 0,1 (8 cp16/wave out). Iter t: gate vmcnt(4)
// certifies stage(t) landed (stage(t+1)'s 4 may fly); barrier publishes all
// waves' gates; stage(t+2) issues +4 (<=8 out). Last iter gates vmcnt(0).
// WAR safety, single barrier/iter: wave Y's ds_reads of buf b at iter t-1
// are retired before its last MFMA (compiler lgkm waits) hence before it
// reaches barrier t; wave X stages into b=(t+2)%3 only after passing
// barrier t. sched_barrier(0) right after the barrier pins the order.
// Everything else (tile 128x128, 4 waves of 64x64 4x4 16x16x32 MFMA, z=4
// split, XCD decode, staging geometry, C-write, reduces, host) is r0-exact
// -> partial math identical, absmax should be bit-identical.
// All prior big rewrites lost (r2 16-wave 2650, r5 32x32 2610, r6 256^2
// phase-split 3003, r4 fence-fusion 14238): minimal-delta only.
// ---------------------------------------------------------------------------
__global__ __launch_bounds__(256, 2) void gemm_splitk_kernel(GJob j0, GJob j1, int nb0)
{
    __shared__ __align__(16) fp16_t As[3][128][32];  // [ring][row][k] 24KB
    __shared__ __align__(16) fp16_t Bs[3][128][32];  // 24KB

    const int tid  = threadIdx.x;
    const int lane = tid & 63;
    const int w    = tid >> 6;         // wave 0..3
    const int wm   = w >> 1;           // m-half (64 rows)
    const int wn   = w & 1;            // n-half (64 cols)
    const int quad = lane >> 4;
    const int lrow = lane & 15;

    int bblk = blockIdx.x;
    const GJob j = (bblk < nb0) ? j0 : j1;       // block-uniform
    if (bblk >= nb0) bblk -= nb0;

    // swizzled decode: bblk%8 = XCD; c = (bn,z) combo pinned to one XCD.
    const int low3 = bblk & 7;
    const int g    = bblk >> 3;
    const int bm   = g & 7;
    const int c    = (g >> 3) * 8 + low3;   // 0..63
    int bn, z;
    if (j.Ntot == 2048) { bn = c >> 2; z = c & 3; }   // 16 bn x 4 z
    else                { bn = c >> 3; z = c & 7; }   // 8 bn x 8 z
    const int k0 = z * j.CK;

    // staging: each cp16 = 16 rows x 32 fp16 (1 KB/wave), lane -> (row=lane/4,
    // col=(lane&3)*8) matches LDS base + lane*16. Wave w owns rows
    // [32w,32w+32) of A and B: 4 cp16/wave per BK=32 tile.
    const int sr = lane >> 2;
    const int sc = (lane & 3) * 8;
    const size_t rowA = (size_t)(bm * 128 + 32 * w + sr);
    const size_t rowB = (size_t)(bn * 128 + 32 * w + sr);
    const fp16_t* a1 = j.A1  + rowA * j.K1 + sc;
    const fp16_t* b1 = j.B1t + rowB * j.K1 + sc;
    const fp16_t* a2 = j.A2  ? j.A2  + rowA * j.K2s + sc : nullptr;
    const fp16_t* b2 = j.B2t ? j.B2t + rowB * j.K2s + sc : nullptr;
    const size_t s16a = (size_t)16 * j.K1;
    const size_t s16b = (size_t)16 * j.K2s;

    auto stage = [&](int buf, int kc) {
        const fp16_t *a0, *b0; size_t st;
        if (kc < j.K1) { a0 = a1 + kc;          b0 = b1 + kc;          st = s16a; }
        else           { a0 = a2 + (kc - j.K1); b0 = b2 + (kc - j.K1); st = s16b; }
        async_cp16(a0,      &As[buf][32 * w     ][0]);
        async_cp16(a0 + st, &As[buf][32 * w + 16][0]);
        async_cp16(b0,      &Bs[buf][32 * w     ][0]);
        async_cp16(b0 + st, &Bs[buf][32 * w + 16][0]);
    };

    v4f acc[4][4] = {};
    const int nt = j.CK >> 5;          // BK = 32

    stage(0, k0);                      // prologue: tiles 0,1 in flight
    stage(1, k0 + 32);

    int cur = 0;
    for (int t = 0; t < nt; ++t) {
        // gate tile t: stage(t) landed; stage(t+1) may stay in flight.
        if (t == nt - 1) asm volatile("s_waitcnt vmcnt(0)" ::: "memory");
        else             asm volatile("s_waitcnt vmcnt(4)" ::: "memory");
        __builtin_amdgcn_s_barrier();            // publish all waves' gates
        __builtin_amdgcn_sched_barrier(0);       // nothing moves across
        if (t + 2 < nt) {
            int nx = cur + 2; if (nx >= 3) nx -= 3;
            stage(nx, k0 + (t + 2) * 32);        // runs ahead, counted by gate
        }
        v8h af[4], bv[4];
        #pragma unroll
        for (int fm = 0; fm < 4; ++fm)
            af[fm] = *(const v8h*)&As[cur][wm * 64 + fm * 16 + lrow][quad * 8];
        #pragma unroll
        for (int fn = 0; fn < 4; ++fn)
            bv[fn] = *(const v8h*)&Bs[cur][wn * 64 + fn * 16 + lrow][quad * 8];
        #pragma unroll
        for (int fm = 0; fm < 4; ++fm)
            #pragma unroll
            for (int fn = 0; fn < 4; ++fn)
                acc[fm][fn] = __builtin_amdgcn_mfma_f32_16x16x32_f16(
                    af[fm], bv[fn], acc[fm][fn], 0, 0, 0);
        cur = (cur + 1 == 3) ? 0 : cur + 1;
    }

    // write fp16 partials. C/D layout: col = lane&15, row = quad*4 + reg.
    fp16_t* po = j.part + (size_t)z * 1024 * j.Ntot;
    const int rowbase = bm * 128 + wm * 64 + quad * 4;
    const int colbase = bn * 128 + wn * 64;
    #pragma unroll
    for (int fn = 0; fn < 4; ++fn) {
        const int col = colbase + fn * 16 + lrow;
        #pragma unroll
        for (int fm = 0; fm < 4; ++fm) {
            const int row = rowbase + fm * 16;
            #pragma unroll
            for (int r = 0; r < 4; ++r)
                po[(size_t)(row + r) * j.Ntot + col] = (fp16_t)acc[fm][fn][r];
        }
    }
}

// Reduce job: sum nz fp16 partial slices + (bias[col] OR per-element fp32
// extra), optional relax-update vs s_old, clip, fp16 state write; optional
// fp32 final output stripped to [1024,1000].
struct RJob {
    const fp16_t* part;
    const float* bias;
    const float* extra;
    const fp16_t* s_old;
    fp16_t* outb;
    float* finout;
    int nz, Ntot, do_update;
};

__global__ __launch_bounds__(256) void reduce_update_kernel(RJob j0, RJob j1, int nb0)
{
    int b = blockIdx.x;
    const RJob j = (b < nb0) ? j0 : j1;          // block-uniform
    if (b >= nb0) b -= nb0;
    const size_t e = ((size_t)b * 256 + threadIdx.x) * 8;  // grids sized exactly

    float v[8];
    {
        const v8h p0 = *(const v8h*)(j.part + e);
        #pragma unroll
        for (int k = 0; k < 8; ++k) v[k] = (float)p0[k];
    }
    for (int z = 1; z < j.nz; ++z) {
        const v8h p = *(const v8h*)(j.part + (size_t)z * 1024 * j.Ntot + e);
        #pragma unroll
        for (int k = 0; k < 8; ++k) v[k] += (float)p[k];
    }
    const int col = (int)e & (j.Ntot - 1);
    if (j.extra) {
        const float4 e0 = *(const float4*)(j.extra + e);
        const float4 e1 = *(const float4*)(j.extra + e + 4);
        v[0] += e0.x; v[1] += e0.y; v[2] += e0.z; v[3] += e0.w;
        v[4] += e1.x; v[5] += e1.y; v[6] += e1.z; v[7] += e1.w;
    } else {
        const float4 b0 = *(const float4*)(j.bias + col);
        const float4 b1 = *(const float4*)(j.bias + col + 4);
        v[0] += b0.x; v[1] += b0.y; v[2] += b0.z; v[3] += b0.w;
        v[4] += b1.x; v[5] += b1.y; v[6] += b1.z; v[7] += b1.w;
    }
    if (j.do_update) {
        const v8h so = *(const v8h*)(j.s_old + e);
        #pragma unroll
        for (int k = 0; k < 8; ++k) {
            const float s = (float)so[k];
            v[k] = s + RELAX_LR * (v[k] - s);
        }
    }
    #pragma unroll
    for (int k = 0; k < 8; ++k) v[k] = fminf(fmaxf(v[k], 0.f), 1.f);
    v8h h;
    #pragma unroll
    for (int k = 0; k < 8; ++k) h[k] = (fp16_t)v[k];
    *(v8h*)(j.outb + e) = h;

    if (j.finout && col < 1000) {
        const int row = (int)(e >> 10);          // Ntot == 1024 on this path
        float* o = j.finout + (size_t)row * 1000 + col;
        float4 o0 = {v[0], v[1], v[2], v[3]};
        float4 o1 = {v[4], v[5], v[6], v[7]};
        *(float4*)o       = o0;
        *(float4*)(o + 4) = o1;
    }
}

// c1f = sum of 4 fp16 partial slices + bias (fp32, no clip): the
// loop-invariant layer-1 constant b1 + rho(x)@W0, computed once.
__global__ __launch_bounds__(256) void makec1_kernel(
    const fp16_t* __restrict__ part, const float* __restrict__ bias,
    float* __restrict__ c1f, int total8)
{
    const int i = blockIdx.x * 256 + threadIdx.x;
    if (i >= total8) return;
    const size_t e = (size_t)i * 8;
    float v[8];
    {
        const v8h p0 = *(const v8h*)(part + e);
        #pragma unroll
        for (int k = 0; k < 8; ++k) v[k] = (float)p0[k];
    }
    #pragma unroll
    for (int z = 1; z < 4; ++z) {
        const v8h p = *(const v8h*)(part + (size_t)z * 1024 * 2048 + e);
        #pragma unroll
        for (int k = 0; k < 8; ++k) v[k] += (float)p[k];
    }
    const int col = (int)e & 2047;
    const float4 b0 = *(const float4*)(bias + col);
    const float4 b1 = *(const float4*)(bias + col + 4);
    v[0] += b0.x; v[1] += b0.y; v[2] += b0.z; v[3] += b0.w;
    v[4] += b1.x; v[5] += b1.y; v[6] += b1.z; v[7] += b1.w;
    float4 o0 = {v[0], v[1], v[2], v[3]};
    float4 o1 = {v[4], v[5], v[6], v[7]};
    *(float4*)(c1f + e)     = o0;
    *(float4*)(c1f + e + 4) = o1;
}

// fp32 W [R,C] -> fp16 Wb [Rp,Cp] (optional) + fp16 WbT [Cp,Rp], zero-padded.
__global__ void conv_w_kernel(const float* __restrict__ W, int R, int C,
                              fp16_t* Wb, fp16_t* __restrict__ WbT,
                              int Rp, int Cp)
{
    __shared__ float t[32][33];
    const int tx = threadIdx.x & 31;
    const int ty = threadIdx.x >> 5;   // 0..7
    const int r0 = blockIdx.y * 32;
    const int c0 = blockIdx.x * 32;
    #pragma unroll
    for (int i = 0; i < 4; ++i) {
        const int r = r0 + ty + i * 8;
        const int c = c0 + tx;
        float v = 0.f;
        if (r < R && c < C) v = W[(size_t)r * C + c];
        t[ty + i * 8][tx] = v;
    }
    __syncthreads();
    if (Wb) {
        #pragma unroll
        for (int i = 0; i < 4; ++i) {
            const int r = r0 + ty + i * 8;
            const int c = c0 + tx;
            if (r < Rp && c < Cp) Wb[(size_t)r * Cp + c] = (fp16_t)t[ty + i * 8][tx];
        }
    }
    #pragma unroll
    for (int i = 0; i < 4; ++i) {
        const int cc = c0 + ty + i * 8;
        const int rr = r0 + tx;
        if (cc < Cp && rr < Rp) WbT[(size_t)cc * Rp + rr] = (fp16_t)t[tx][ty + i * 8];
    }
}

__global__ void conv_x_kernel(const float* __restrict__ x,
                              fp16_t* __restrict__ xb, fp16_t* __restrict__ rxb, int n)
{
    const int i = blockIdx.x * blockDim.x + threadIdx.x;
    if (i < n) {
        const float v = x[i];
        xb[i]  = (fp16_t)v;
        rxb[i] = (fp16_t)fminf(fmaxf(v, 0.f), 1.f);
    }
}

__global__ void pad_b4_kernel(const float* __restrict__ b4, float* __restrict__ b4p)
{
    const int i = blockIdx.x * blockDim.x + threadIdx.x;
    if (i < 1024) b4p[i] = (i < 1000) ? b4[i] : 0.f;
}

extern "C" void kernel_launch(void* const* d_in, const int* in_sizes, int n_in,
                              void* d_out, int out_size, void* d_ws, size_t ws_size,
                              hipStream_t stream)
{
    const float* x  = (const float*)d_in[0];
    const float* W0 = (const float*)d_in[1];
    const float* W1 = (const float*)d_in[2];
    const float* W2 = (const float*)d_in[3];
    const float* W3 = (const float*)d_in[4];
    const float* b1 = (const float*)d_in[5];
    const float* b2 = (const float*)d_in[6];
    const float* b3 = (const float*)d_in[7];
    const float* b4 = (const float*)d_in[8];
    float* out = (float*)d_out;

    char* p = (char*)d_ws;
    auto alloc = [&](size_t bytes) {
        char* q = p;
        p += (bytes + 255) & ~(size_t)255;
        return q;
    };

    fp16_t* xb    = (fp16_t*)alloc((size_t)1024 * 2048 * 2);
    fp16_t* rxb   = (fp16_t*)alloc((size_t)1024 * 2048 * 2);
    fp16_t* Wb1   = (fp16_t*)alloc((size_t)2048 * 2048 * 2);
    fp16_t* Wb2   = (fp16_t*)alloc((size_t)2048 * 2048 * 2);
    fp16_t* Wb3   = (fp16_t*)alloc((size_t)2048 * 1024 * 2);   // padded cols
    fp16_t* WbT0  = (fp16_t*)alloc((size_t)2048 * 2048 * 2);
    fp16_t* WbT1  = (fp16_t*)alloc((size_t)2048 * 2048 * 2);
    fp16_t* WbT2  = (fp16_t*)alloc((size_t)2048 * 2048 * 2);
    fp16_t* WbT3  = (fp16_t*)alloc((size_t)1024 * 2048 * 2);   // padded rows
    fp16_t* s1b   = (fp16_t*)alloc((size_t)1024 * 2048 * 2);
    fp16_t* s2b   = (fp16_t*)alloc((size_t)1024 * 2048 * 2);
    fp16_t* s3b   = (fp16_t*)alloc((size_t)1024 * 2048 * 2);
    fp16_t* s4b   = (fp16_t*)alloc((size_t)1024 * 1024 * 2);
    float*  b4p   = (float*)alloc(1024 * 4);
    float*  c1f   = (float*)alloc((size_t)1024 * 2048 * 4);    // hoisted b1+rho(x)@W0
    fp16_t* partA = (fp16_t*)alloc((size_t)8 * 1024 * 1024 * 2); // 16 MB (L4 jobs)
    fp16_t* partB = (fp16_t*)alloc((size_t)4 * 1024 * 2048 * 2); // 16 MB (L1-3 jobs)
    (void)ws_size; (void)in_sizes; (void)n_in; (void)out_size;

    // --- setup conversions ---
    conv_x_kernel<<<(1024 * 2048 + 255) / 256, 256, 0, stream>>>(x, xb, rxb, 1024 * 2048);
    pad_b4_kernel<<<4, 256, 0, stream>>>(b4, b4p);
    conv_w_kernel<<<dim3(64, 64), 256, 0, stream>>>(W0, 2048, 2048, nullptr, WbT0, 2048, 2048);
    conv_w_kernel<<<dim3(64, 64), 256, 0, stream>>>(W1, 2048, 2048, Wb1, WbT1, 2048, 2048);
    conv_w_kernel<<<dim3(64, 64), 256, 0, stream>>>(W2, 2048, 2048, Wb2, WbT2, 2048, 2048);
    conv_w_kernel<<<dim3(32, 64), 256, 0, stream>>>(W3, 2048, 1000, Wb3, WbT3, 2048, 1024);

    const dim3 blk(256);
    const int rg2048 = 1024 * 2048 / 8 / 256;   // 1024 blocks
    const int rg1024 = 1024 * 1024 / 8 / 256;   // 512 blocks

    // --- GEMM jobs (A1,B1t,A2,B2t,part,K1,K2s,CK,Ntot) ---
    const GJob jC1 = { rxb, WbT0, nullptr, nullptr, partA, 2048, 0,    512,  2048 };
    const GJob jI1 = { xb,  WbT0, nullptr, nullptr, partB, 2048, 0,    512,  2048 };
    const GJob jI2 = { s1b, WbT1, nullptr, nullptr, partB, 2048, 0,    512,  2048 };
    const GJob jI3 = { s2b, WbT2, nullptr, nullptr, partB, 2048, 0,    512,  2048 };
    const GJob jI4 = { s3b, WbT3, nullptr, nullptr, partA, 2048, 0,    256,  1024 };
    const GJob jL1 = { s2b, Wb1,  nullptr, nullptr, partB, 2048, 0,    512,  2048 };
    const GJob jL2 = { s1b, WbT1, s3b, Wb2,         partB, 2048, 2048, 1024, 2048 };
    const GJob jL3 = { s2b, WbT2, s4b, Wb3,         partB, 2048, 1024, 768,  2048 }; // balanced 4x768, chunk 2 crosses
    const GJob jL4 = { s3b, WbT3, nullptr, nullptr, partA, 2048, 0,    256,  1024 };

    // --- reduce jobs (part,bias,extra,s_old,outb,finout,nz,Ntot,do_update) ---
    const RJob rI1 = { partB, b1,  nullptr, nullptr, s1b, nullptr, 4, 2048, 0 };
    const RJob rI2 = { partB, b2,  nullptr, nullptr, s2b, nullptr, 4, 2048, 0 };
    const RJob rI3 = { partB, b3,  nullptr, nullptr, s3b, nullptr, 4, 2048, 0 };
    const RJob rI4 = { partA, b4p, nullptr, nullptr, s4b, nullptr, 8, 1024, 0 };
    const RJob rL1 = { partB, nullptr, c1f, s1b, s1b, nullptr, 4, 2048, 1 };
    const RJob rL2 = { partB, b2,  nullptr, s2b, s2b, nullptr, 4, 2048, 1 };
    const RJob rL3 = { partB, b3,  nullptr, s3b, s3b, nullptr, 4, 2048, 1 };
    const RJob rL4 = { partA, b4p, nullptr, s4b, s4b, nullptr, 8, 1024, 1 };
    RJob rL4f = rL4; rL4f.finout = out;

    // --- hoisted layer-1 constant: c1f = b1 + rho(x)@W0 (once, reused 25x) ---
    gemm_splitk_kernel<<<512, blk, 0, stream>>>(jC1, jC1, 512);
    makec1_kernel<<<rg2048, blk, 0, stream>>>(partA, b1, c1f, 1024 * 2048 / 8);

    // --- feedforward init: s_l = clip(s_{l-1} @ W_{l-1} + b_l) ---
    gemm_splitk_kernel<<<512, blk, 0, stream>>>(jI1, jI1, 512);
    reduce_update_kernel<<<rg2048, blk, 0, stream>>>(rI1, rI1, rg2048);
    gemm_splitk_kernel<<<512, blk, 0, stream>>>(jI2, jI2, 512);
    reduce_update_kernel<<<rg2048, blk, 0, stream>>>(rI2, rI2, rg2048);
    gemm_splitk_kernel<<<512, blk, 0, stream>>>(jI3, jI3, 512);
    reduce_update_kernel<<<rg2048, blk, 0, stream>>>(rI3, rI3, rg2048);
    gemm_splitk_kernel<<<512, blk, 0, stream>>>(jI4, jI4, 512);
    reduce_update_kernel<<<rg1024, blk, 0, stream>>>(rI4, rI4, rg1024);

    // --- 25 Gauss-Seidel sweeps. Layer order per sweep is L1,L2,L3,L4, but
    // L4(sweep it) and L1(sweep it+1) are mutually independent (L4 reads s3,
    // L1 reads s2 + c1f) -> merged into one GEMM + one reduce dispatch. ---
    gemm_splitk_kernel<<<512, blk, 0, stream>>>(jL1, jL1, 512);          // L1, sweep 0
    reduce_update_kernel<<<rg2048, blk, 0, stream>>>(rL1, rL1, rg2048);
    for (int it = 0; it < 25; ++it) {
        gemm_splitk_kernel<<<512, blk, 0, stream>>>(jL2, jL2, 512);
        reduce_update_kernel<<<rg2048, blk, 0, stream>>>(rL2, rL2, rg2048);
        gemm_splitk_kernel<<<512, blk, 0, stream>>>(jL3, jL3, 512);
        reduce_update_kernel<<<rg2048, blk, 0, stream>>>(rL3, rL3, rg2048);
        if (it < 24) {
            gemm_splitk_kernel<<<1024, blk, 0, stream>>>(jL4, jL1, 512); // L4 + next L1
            reduce_update_kernel<<<rg1024 + rg2048, blk, 0, stream>>>(rL4, rL1, rg1024);
        } else {
            gemm_splitk_kernel<<<512, blk, 0, stream>>>(jL4, jL4, 512);
            reduce_update_kernel<<<rg1024, blk, 0, stream>>>(rL4f, rL4f, rg1024);
        }
    }
}

// Round 9
// 2414.082 us; speedup vs baseline: 1.2439x; 1.1057x over previous
//
#include <hip/hip_runtime.h>
#include <hip/hip_bf16.h>

typedef _Float16 fp16_t;
typedef _Float16 v8h __attribute__((ext_vector_type(8)));
typedef float    v4f __attribute__((ext_vector_type(4)));

#define RELAX_LR 0.3f

// async global->LDS, 16B per lane. LDS dest = wave-uniform base + lane*16.
__device__ __forceinline__ void async_cp16(const void* g, void* l) {
    __builtin_amdgcn_global_load_lds(
        (const __attribute__((address_space(1))) void*)g,
        (__attribute__((address_space(3))) void*)l, 16, 0, 0);
}

// GEMM job: C_partial(z) = A1*B1t^T (concat K-space [0,K1)) ++ A2*B2t^T
// ([K1,K1+K2s)). Chunk z covers [z*CK,(z+1)*CK) and MAY cross the section
// boundary (both K1 and chunks are multiples of BK=64, so a BK-tile never
// straddles; pointer select per BK-iter is block-uniform scalar work).
struct GJob {
    const fp16_t *A1, *B1t, *A2, *B2t;
    fp16_t* part;
    int K1, K2s, CK, Ntot;
};

// ---------------------------------------------------------------------------
// Session champion (2407us), restored exact. Two-job split-K GEMM into fp16
// partials (fp32 MFMA accumulate, one rounding at store). Blocks [0,nb0) run
// j0, [nb0,grid) run j1. Tile BM=128 x BN=128 x BK=64, 256 thr = 4 waves,
// each wave 64x64 (4x4 16x16x32 f16 MFMA). Double-buffered LDS 64 KB ->
// 2 blocks/CU (8 waves/CU). XCD-swizzled decode (blk%8 = XCD; z pinned per
// XCD -> ~3MB L2 working set).
// Measured dead ends (do NOT revisit): BK=32/z=8 16-wave (r2: 2650, +r8
// counted-vmcnt 3-ring: 2669 -- the syncthreads vmcnt(0) drain is already
// hidden by the other resident block's compute, and halving BK doubles
// barrier cost); 32x32x16 MFMA + slot swizzle (r5: 2610 -- fragment
// bytes/FLOP set by wave-tile size, not MFMA shape); 256^2 8-wave phase
// split at 1 blk/CU (r6: 3003); epilogue fusion via election + threadfence
// (r4: 14238 -- per-block agent fences = per-XCD L2 writeback/invalidate
// storm); single-kernel full-K fusion (r1: 3226).
// ---------------------------------------------------------------------------
__global__ __launch_bounds__(256, 2) void gemm_splitk_kernel(GJob j0, GJob j1, int nb0)
{
    __shared__ __align__(16) fp16_t As[2][2][128][32];  // [stage][khalf][row][col]
    __shared__ __align__(16) fp16_t Bs[2][2][128][32];

    const int tid  = threadIdx.x;
    const int lane = tid & 63;
    const int w    = tid >> 6;         // wave 0..3
    const int wm   = w >> 1;           // m-half (64 rows)
    const int wn   = w & 1;            // n-half (64 cols)
    const int quad = lane >> 4;
    const int lrow = lane & 15;

    int bblk = blockIdx.x;
    const GJob j = (bblk < nb0) ? j0 : j1;       // block-uniform
    if (bblk >= nb0) bblk -= nb0;

    // swizzled decode: bblk%8 = XCD; c = (bn,z) combo pinned to one XCD.
    const int low3 = bblk & 7;
    const int g    = bblk >> 3;
    const int bm   = g & 7;
    const int c    = (g >> 3) * 8 + low3;   // 0..63
    int bn, z;
    if (j.Ntot == 2048) { bn = c >> 2; z = c & 3; }   // 16 bn x 4 z
    else                { bn = c >> 3; z = c & 7; }   // 8 bn x 8 z
    const int k0 = z * j.CK;

    // staging: each cp16 = 16 rows x 32 fp16 (1 KB/wave), lane -> (row=lane/4,
    // col=(lane&3)*8) matches LDS base + lane*16. Wave w owns rows
    // [32w,32w+32) of A and B for both khalves: 8 cp16/wave per stage.
    const int sr = lane >> 2;
    const int sc = (lane & 3) * 8;
    const size_t rowA = (size_t)(bm * 128 + 32 * w + sr);
    const size_t rowB = (size_t)(bn * 128 + 32 * w + sr);
    const fp16_t* a1 = j.A1  + rowA * j.K1 + sc;
    const fp16_t* b1 = j.B1t + rowB * j.K1 + sc;
    const fp16_t* a2 = j.A2  ? j.A2  + rowA * j.K2s + sc : nullptr;
    const fp16_t* b2 = j.B2t ? j.B2t + rowB * j.K2s + sc : nullptr;
    const size_t s16a = (size_t)16 * j.K1;
    const size_t s16b = (size_t)16 * j.K2s;

    auto stage = [&](int buf, int kc) {
        const fp16_t *a0, *b0; size_t st;
        if (kc < j.K1) { a0 = a1 + kc;          b0 = b1 + kc;          st = s16a; }
        else           { a0 = a2 + (kc - j.K1); b0 = b2 + (kc - j.K1); st = s16b; }
        async_cp16(a0,           &As[buf][0][32 * w     ][0]);
        async_cp16(a0 + st,      &As[buf][0][32 * w + 16][0]);
        async_cp16(a0 + 32,      &As[buf][1][32 * w     ][0]);
        async_cp16(a0 + 32 + st, &As[buf][1][32 * w + 16][0]);
        async_cp16(b0,           &Bs[buf][0][32 * w     ][0]);
        async_cp16(b0 + st,      &Bs[buf][0][32 * w + 16][0]);
        async_cp16(b0 + 32,      &Bs[buf][1][32 * w     ][0]);
        async_cp16(b0 + 32 + st, &Bs[buf][1][32 * w + 16][0]);
    };

    v4f acc[4][4] = {};
    const int iters = j.CK >> 6;       // BK = 64

    stage(0, k0);                      // prologue: tile 0 -> buffer 0

    for (int it = 0; it < iters; ++it) {
        __syncthreads();   // drains vmcnt -> buf (it&1) ready; prior ds_reads done
        if (it + 1 < iters) stage((it + 1) & 1, k0 + (it + 1) * 64);
        const int cur = it & 1;
        #pragma unroll
        for (int h = 0; h < 2; ++h) {
            v8h af[4], bv[4];
            #pragma unroll
            for (int fm = 0; fm < 4; ++fm)
                af[fm] = *(const v8h*)&As[cur][h][wm * 64 + fm * 16 + lrow][quad * 8];
            #pragma unroll
            for (int fn = 0; fn < 4; ++fn)
                bv[fn] = *(const v8h*)&Bs[cur][h][wn * 64 + fn * 16 + lrow][quad * 8];
            #pragma unroll
            for (int fm = 0; fm < 4; ++fm)
                #pragma unroll
                for (int fn = 0; fn < 4; ++fn)
                    acc[fm][fn] = __builtin_amdgcn_mfma_f32_16x16x32_f16(
                        af[fm], bv[fn], acc[fm][fn], 0, 0, 0);
        }
    }

    // write fp16 partials. C/D layout: col = lane&15, row = quad*4 + reg.
    fp16_t* po = j.part + (size_t)z * 1024 * j.Ntot;
    const int rowbase = bm * 128 + wm * 64 + quad * 4;
    const int colbase = bn * 128 + wn * 64;
    #pragma unroll
    for (int fn = 0; fn < 4; ++fn) {
        const int col = colbase + fn * 16 + lrow;
        #pragma unroll
        for (int fm = 0; fm < 4; ++fm) {
            const int row = rowbase + fm * 16;
            #pragma unroll
            for (int r = 0; r < 4; ++r)
                po[(size_t)(row + r) * j.Ntot + col] = (fp16_t)acc[fm][fn][r];
        }
    }
}

// Reduce job: sum nz fp16 partial slices + (bias[col] OR per-element fp32
// extra), optional relax-update vs s_old, clip, fp16 state write; optional
// fp32 final output stripped to [1024,1000].
struct RJob {
    const fp16_t* part;
    const float* bias;
    const float* extra;
    const fp16_t* s_old;
    fp16_t* outb;
    float* finout;
    int nz, Ntot, do_update;
};

__global__ __launch_bounds__(256) void reduce_update_kernel(RJob j0, RJob j1, int nb0)
{
    int b = blockIdx.x;
    const RJob j = (b < nb0) ? j0 : j1;          // block-uniform
    if (b >= nb0) b -= nb0;
    const size_t e = ((size_t)b * 256 + threadIdx.x) * 8;  // grids sized exactly

    float v[8];
    {
        const v8h p0 = *(const v8h*)(j.part + e);
        #pragma unroll
        for (int k = 0; k < 8; ++k) v[k] = (float)p0[k];
    }
    for (int z = 1; z < j.nz; ++z) {
        const v8h p = *(const v8h*)(j.part + (size_t)z * 1024 * j.Ntot + e);
        #pragma unroll
        for (int k = 0; k < 8; ++k) v[k] += (float)p[k];
    }
    const int col = (int)e & (j.Ntot - 1);
    if (j.extra) {
        const float4 e0 = *(const float4*)(j.extra + e);
        const float4 e1 = *(const float4*)(j.extra + e + 4);
        v[0] += e0.x; v[1] += e0.y; v[2] += e0.z; v[3] += e0.w;
        v[4] += e1.x; v[5] += e1.y; v[6] += e1.z; v[7] += e1.w;
    } else {
        const float4 b0 = *(const float4*)(j.bias + col);
        const float4 b1 = *(const float4*)(j.bias + col + 4);
        v[0] += b0.x; v[1] += b0.y; v[2] += b0.z; v[3] += b0.w;
        v[4] += b1.x; v[5] += b1.y; v[6] += b1.z; v[7] += b1.w;
    }
    if (j.do_update) {
        const v8h so = *(const v8h*)(j.s_old + e);
        #pragma unroll
        for (int k = 0; k < 8; ++k) {
            const float s = (float)so[k];
            v[k] = s + RELAX_LR * (v[k] - s);
        }
    }
    #pragma unroll
    for (int k = 0; k < 8; ++k) v[k] = fminf(fmaxf(v[k], 0.f), 1.f);
    v8h h;
    #pragma unroll
    for (int k = 0; k < 8; ++k) h[k] = (fp16_t)v[k];
    *(v8h*)(j.outb + e) = h;

    if (j.finout && col < 1000) {
        const int row = (int)(e >> 10);          // Ntot == 1024 on this path
        float* o = j.finout + (size_t)row * 1000 + col;
        float4 o0 = {v[0], v[1], v[2], v[3]};
        float4 o1 = {v[4], v[5], v[6], v[7]};
        *(float4*)o       = o0;
        *(float4*)(o + 4) = o1;
    }
}

// c1f = sum of 4 fp16 partial slices + bias (fp32, no clip): the
// loop-invariant layer-1 constant b1 + rho(x)@W0, computed once.
__global__ __launch_bounds__(256) void makec1_kernel(
    const fp16_t* __restrict__ part, const float* __restrict__ bias,
    float* __restrict__ c1f, int total8)
{
    const int i = blockIdx.x * 256 + threadIdx.x;
    if (i >= total8) return;
    const size_t e = (size_t)i * 8;
    float v[8];
    {
        const v8h p0 = *(const v8h*)(part + e);
        #pragma unroll
        for (int k = 0; k < 8; ++k) v[k] = (float)p0[k];
    }
    #pragma unroll
    for (int z = 1; z < 4; ++z) {
        const v8h p = *(const v8h*)(part + (size_t)z * 1024 * 2048 + e);
        #pragma unroll
        for (int k = 0; k < 8; ++k) v[k] += (float)p[k];
    }
    const int col = (int)e & 2047;
    const float4 b0 = *(const float4*)(bias + col);
    const float4 b1 = *(const float4*)(bias + col + 4);
    v[0] += b0.x; v[1] += b0.y; v[2] += b0.z; v[3] += b0.w;
    v[4] += b1.x; v[5] += b1.y; v[6] += b1.z; v[7] += b1.w;
    float4 o0 = {v[0], v[1], v[2], v[3]};
    float4 o1 = {v[4], v[5], v[6], v[7]};
    *(float4*)(c1f + e)     = o0;
    *(float4*)(c1f + e + 4) = o1;
}

// fp32 W [R,C] -> fp16 Wb [Rp,Cp] (optional) + fp16 WbT [Cp,Rp], zero-padded.
__global__ void conv_w_kernel(const float* __restrict__ W, int R, int C,
                              fp16_t* Wb, fp16_t* __restrict__ WbT,
                              int Rp, int Cp)
{
    __shared__ float t[32][33];
    const int tx = threadIdx.x & 31;
    const int ty = threadIdx.x >> 5;   // 0..7
    const int r0 = blockIdx.y * 32;
    const int c0 = blockIdx.x * 32;
    #pragma unroll
    for (int i = 0; i < 4; ++i) {
        const int r = r0 + ty + i * 8;
        const int c = c0 + tx;
        float v = 0.f;
        if (r < R && c < C) v = W[(size_t)r * C + c];
        t[ty + i * 8][tx] = v;
    }
    __syncthreads();
    if (Wb) {
        #pragma unroll
        for (int i = 0; i < 4; ++i) {
            const int r = r0 + ty + i * 8;
            const int c = c0 + tx;
            if (r < Rp && c < Cp) Wb[(size_t)r * Cp + c] = (fp16_t)t[ty + i * 8][tx];
        }
    }
    #pragma unroll
    for (int i = 0; i < 4; ++i) {
        const int cc = c0 + ty + i * 8;
        const int rr = r0 + tx;
        if (cc < Cp && rr < Rp) WbT[(size_t)cc * Rp + rr] = (fp16_t)t[tx][ty + i * 8];
    }
}

__global__ void conv_x_kernel(const float* __restrict__ x,
                              fp16_t* __restrict__ xb, fp16_t* __restrict__ rxb, int n)
{
    const int i = blockIdx.x * blockDim.x + threadIdx.x;
    if (i < n) {
        const float v = x[i];
        xb[i]  = (fp16_t)v;
        rxb[i] = (fp16_t)fminf(fmaxf(v, 0.f), 1.f);
    }
}

__global__ void pad_b4_kernel(const float* __restrict__ b4, float* __restrict__ b4p)
{
    const int i = blockIdx.x * blockDim.x + threadIdx.x;
    if (i < 1024) b4p[i] = (i < 1000) ? b4[i] : 0.f;
}

extern "C" void kernel_launch(void* const* d_in, const int* in_sizes, int n_in,
                              void* d_out, int out_size, void* d_ws, size_t ws_size,
                              hipStream_t stream)
{
    const float* x  = (const float*)d_in[0];
    const float* W0 = (const float*)d_in[1];
    const float* W1 = (const float*)d_in[2];
    const float* W2 = (const float*)d_in[3];
    const float* W3 = (const float*)d_in[4];
    const float* b1 = (const float*)d_in[5];
    const float* b2 = (const float*)d_in[6];
    const float* b3 = (const float*)d_in[7];
    const float* b4 = (const float*)d_in[8];
    float* out = (float*)d_out;

    char* p = (char*)d_ws;
    auto alloc = [&](size_t bytes) {
        char* q = p;
        p += (bytes + 255) & ~(size_t)255;
        return q;
    };

    fp16_t* xb    = (fp16_t*)alloc((size_t)1024 * 2048 * 2);
    fp16_t* rxb   = (fp16_t*)alloc((size_t)1024 * 2048 * 2);
    fp16_t* Wb1   = (fp16_t*)alloc((size_t)2048 * 2048 * 2);
    fp16_t* Wb2   = (fp16_t*)alloc((size_t)2048 * 2048 * 2);
    fp16_t* Wb3   = (fp16_t*)alloc((size_t)2048 * 1024 * 2);   // padded cols
    fp16_t* WbT0  = (fp16_t*)alloc((size_t)2048 * 2048 * 2);
    fp16_t* WbT1  = (fp16_t*)alloc((size_t)2048 * 2048 * 2);
    fp16_t* WbT2  = (fp16_t*)alloc((size_t)2048 * 2048 * 2);
    fp16_t* WbT3  = (fp16_t*)alloc((size_t)1024 * 2048 * 2);   // padded rows
    fp16_t* s1b   = (fp16_t*)alloc((size_t)1024 * 2048 * 2);
    fp16_t* s2b   = (fp16_t*)alloc((size_t)1024 * 2048 * 2);
    fp16_t* s3b   = (fp16_t*)alloc((size_t)1024 * 2048 * 2);
    fp16_t* s4b   = (fp16_t*)alloc((size_t)1024 * 1024 * 2);
    float*  b4p   = (float*)alloc(1024 * 4);
    float*  c1f   = (float*)alloc((size_t)1024 * 2048 * 4);    // hoisted b1+rho(x)@W0
    fp16_t* partA = (fp16_t*)alloc((size_t)8 * 1024 * 1024 * 2); // 16 MB (L4 jobs)
    fp16_t* partB = (fp16_t*)alloc((size_t)4 * 1024 * 2048 * 2); // 16 MB (L1-3 jobs)
    (void)ws_size; (void)in_sizes; (void)n_in; (void)out_size;

    // --- setup conversions ---
    conv_x_kernel<<<(1024 * 2048 + 255) / 256, 256, 0, stream>>>(x, xb, rxb, 1024 * 2048);
    pad_b4_kernel<<<4, 256, 0, stream>>>(b4, b4p);
    conv_w_kernel<<<dim3(64, 64), 256, 0, stream>>>(W0, 2048, 2048, nullptr, WbT0, 2048, 2048);
    conv_w_kernel<<<dim3(64, 64), 256, 0, stream>>>(W1, 2048, 2048, Wb1, WbT1, 2048, 2048);
    conv_w_kernel<<<dim3(64, 64), 256, 0, stream>>>(W2, 2048, 2048, Wb2, WbT2, 2048, 2048);
    conv_w_kernel<<<dim3(32, 64), 256, 0, stream>>>(W3, 2048, 1000, Wb3, WbT3, 2048, 1024);

    const dim3 blk(256);
    const int rg2048 = 1024 * 2048 / 8 / 256;   // 1024 blocks
    const int rg1024 = 1024 * 1024 / 8 / 256;   // 512 blocks

    // --- GEMM jobs (A1,B1t,A2,B2t,part,K1,K2s,CK,Ntot) ---
    const GJob jC1 = { rxb, WbT0, nullptr, nullptr, partA, 2048, 0,    512,  2048 };
    const GJob jI1 = { xb,  WbT0, nullptr, nullptr, partB, 2048, 0,    512,  2048 };
    const GJob jI2 = { s1b, WbT1, nullptr, nullptr, partB, 2048, 0,    512,  2048 };
    const GJob jI3 = { s2b, WbT2, nullptr, nullptr, partB, 2048, 0,    512,  2048 };
    const GJob jI4 = { s3b, WbT3, nullptr, nullptr, partA, 2048, 0,    256,  1024 };
    const GJob jL1 = { s2b, Wb1,  nullptr, nullptr, partB, 2048, 0,    512,  2048 };
    const GJob jL2 = { s1b, WbT1, s3b, Wb2,         partB, 2048, 2048, 1024, 2048 };
    const GJob jL3 = { s2b, WbT2, s4b, Wb3,         partB, 2048, 1024, 768,  2048 }; // balanced 4x768, chunk 2 crosses
    const GJob jL4 = { s3b, WbT3, nullptr, nullptr, partA, 2048, 0,    256,  1024 };

    // --- reduce jobs (part,bias,extra,s_old,outb,finout,nz,Ntot,do_update) ---
    const RJob rI1 = { partB, b1,  nullptr, nullptr, s1b, nullptr, 4, 2048, 0 };
    const RJob rI2 = { partB, b2,  nullptr, nullptr, s2b, nullptr, 4, 2048, 0 };
    const RJob rI3 = { partB, b3,  nullptr, nullptr, s3b, nullptr, 4, 2048, 0 };
    const RJob rI4 = { partA, b4p, nullptr, nullptr, s4b, nullptr, 8, 1024, 0 };
    const RJob rL1 = { partB, nullptr, c1f, s1b, s1b, nullptr, 4, 2048, 1 };
    const RJob rL2 = { partB, b2,  nullptr, s2b, s2b, nullptr, 4, 2048, 1 };
    const RJob rL3 = { partB, b3,  nullptr, s3b, s3b, nullptr, 4, 2048, 1 };
    const RJob rL4 = { partA, b4p, nullptr, s4b, s4b, nullptr, 8, 1024, 1 };
    RJob rL4f = rL4; rL4f.finout = out;

    // --- hoisted layer-1 constant: c1f = b1 + rho(x)@W0 (once, reused 25x) ---
    gemm_splitk_kernel<<<512, blk, 0, stream>>>(jC1, jC1, 512);
    makec1_kernel<<<rg2048, blk, 0, stream>>>(partA, b1, c1f, 1024 * 2048 / 8);

    // --- feedforward init: s_l = clip(s_{l-1} @ W_{l-1} + b_l) ---
    gemm_splitk_kernel<<<512, blk, 0, stream>>>(jI1, jI1, 512);
    reduce_update_kernel<<<rg2048, blk, 0, stream>>>(rI1, rI1, rg2048);
    gemm_splitk_kernel<<<512, blk, 0, stream>>>(jI2, jI2, 512);
    reduce_update_kernel<<<rg2048, blk, 0, stream>>>(rI2, rI2, rg2048);
    gemm_splitk_kernel<<<512, blk, 0, stream>>>(jI3, jI3, 512);
    reduce_update_kernel<<<rg2048, blk, 0, stream>>>(rI3, rI3, rg2048);
    gemm_splitk_kernel<<<512, blk, 0, stream>>>(jI4, jI4, 512);
    reduce_update_kernel<<<rg1024, blk, 0, stream>>>(rI4, rI4, rg1024);

    // --- 25 Gauss-Seidel sweeps. Layer order per sweep is L1,L2,L3,L4, but
    // L4(sweep it) and L1(sweep it+1) are mutually independent (L4 reads s3,
    // L1 reads s2 + c1f) -> merged into one GEMM + one reduce dispatch. ---
    gemm_splitk_kernel<<<512, blk, 0, stream>>>(jL1, jL1, 512);          // L1, sweep 0
    reduce_update_kernel<<<rg2048, blk, 0, stream>>>(rL1, rL1, rg2048);
    for (int it = 0; it < 25; ++it) {
        gemm_splitk_kernel<<<512, blk, 0, stream>>>(jL2, jL2, 512);
        reduce_update_kernel<<<rg2048, blk, 0, stream>>>(rL2, rL2, rg2048);
        gemm_splitk_kernel<<<512, blk, 0, stream>>>(jL3, jL3, 512);
        reduce_update_kernel<<<rg2048, blk, 0, stream>>>(rL3, rL3, rg2048);
        if (it < 24) {
            gemm_splitk_kernel<<<1024, blk, 0, stream>>>(jL4, jL1, 512); // L4 + next L1
            reduce_update_kernel<<<rg1024 + rg2048, blk, 0, stream>>>(rL4, rL1, rg1024);
        } else {
            gemm_splitk_kernel<<<512, blk, 0, stream>>>(jL4, jL4, 512);
            reduce_update_kernel<<<rg1024, blk, 0, stream>>>(rL4f, rL4f, rg1024);
        }
    }
}